// Round 6
// baseline (2092.155 us; speedup 1.0000x reference)
//
#include <hip/hip_runtime.h>
#include <math.h>

typedef __bf16 bf16x8 __attribute__((ext_vector_type(8)));
typedef float  f32x16 __attribute__((ext_vector_type(16)));

static __device__ __forceinline__ f32x16 MFMA(bf16x8 a, bf16x8 b, f32x16 c){
  return __builtin_amdgcn_mfma_f32_32x32x16_bf16(a, b, c, 0, 0, 0);
}
static __device__ __forceinline__ unsigned short f2bf(float x){
  unsigned int u = __builtin_bit_cast(unsigned int, x);
  u += 0x7fffu + ((u >> 16) & 1u);   // RNE
  return (unsigned short)(u >> 16);
}
static __device__ __forceinline__ unsigned int pack2(float a, float b){
  return ((unsigned int)f2bf(b) << 16) | (unsigned int)f2bf(a);
}
static __device__ __forceinline__ bf16x8 ldfrag(const unsigned short* p){
  return __builtin_bit_cast(bf16x8, *(const uint4*)p);
}
// C-layout row for 32x32x16: row = (reg&3) + 8*(reg>>2) + 4*(lane>>5)
static __device__ __forceinline__ int rowmap(int reg, int lane){
  return (reg & 3) + 8 * (reg >> 2) + 4 * (lane >> 5);
}

// ------------------------------------------------ weight transpose+cast (once)
__global__ __launch_bounds__(256) void k_wprep(const float* __restrict__ in_w,
    const float* __restrict__ q_w, const float* __restrict__ k_w,
    const float* __restrict__ v_w, unsigned short* __restrict__ wT){
  int idx = blockIdx.x * 256 + threadIdx.x;   // 983040 total
  float v;
  if (idx < 98304){
    int c = idx / 384, k = idx % 384;
    v = in_w[k * 256 + c];
  } else {
    int e = idx - 98304;
    int m = e / 73728, r = e % 73728;
    int c = r / 288, k = r % 288;
    int p = m % 3, layer = m / 3;
    const float* src = (p == 0) ? q_w : (p == 1) ? k_w : v_w;
    v = src[(size_t)layer * 73728 + k * 256 + c];
  }
  wT[idx] = f2bf(v);
}

// ------------------------------------------------ temporal emb (bf16, masked)
__global__ __launch_bounds__(256) void k_temporal(const float* __restrict__ tim,
                                                  unsigned int* __restrict__ tem){
  int idx = blockIdx.x * 256 + threadIdx.x;   // 65536*16
  int i = idx & 15, m = idx >> 4;
  float t = tim[m];
  float np = (t > 0.0f) ? 1.0f : 0.0f;
  float dv = expf((float)(2 * i) * (-0.28782313662425576f));
  float arg = t * dv;
  tem[m * 16 + i] = pack2(sinf(arg) * np, cosf(arg) * np);
}

// ------------------------------------------------ input projection (MFMA)
__global__ __launch_bounds__(256, 2) void k_inproj(const int* __restrict__ subj,
    const int* __restrict__ obj, const int* __restrict__ rel,
    const float* __restrict__ ent, const float* __restrict__ rele,
    const unsigned short* __restrict__ inwT, const float* __restrict__ in_b,
    unsigned short* __restrict__ enc){
  __shared__ __align__(16) unsigned short A[64 * 392];  // reused as SB[64*264] after
  int t = threadIdx.x;
  int m0 = blockIdx.x * 64;
  { // gather 64 rows of concat(ent[s],ent[o],rel[r]) as bf16
    int r = t >> 2, c = t & 3;
    int m = m0 + r;
    const float4* s0 = (const float4*)(ent  + (size_t)subj[m] * 128 + c * 32);
    const float4* s1 = (const float4*)(ent  + (size_t)obj[m]  * 128 + c * 32);
    const float4* s2 = (const float4*)(rele + (size_t)rel[m]  * 128 + c * 32);
    unsigned int* dst = (unsigned int*)&A[r * 392];
#pragma unroll
    for (int j = 0; j < 8; j++){
      float4 f0 = s0[j], f1 = s1[j], f2 = s2[j];
      dst[c * 16 + 2 * j]           = pack2(f0.x, f0.y);
      dst[c * 16 + 2 * j + 1]       = pack2(f0.z, f0.w);
      dst[64 + c * 16 + 2 * j]      = pack2(f1.x, f1.y);
      dst[64 + c * 16 + 2 * j + 1]  = pack2(f1.z, f1.w);
      dst[128 + c * 16 + 2 * j]     = pack2(f2.x, f2.y);
      dst[128 + c * 16 + 2 * j + 1] = pack2(f2.z, f2.w);
    }
  }
  __syncthreads();
  int w = t >> 6, lane = t & 63;
  int lrow = lane & 31, khalf = (lane >> 5) * 8;
  int colA = (w * 2) * 32 + lrow, colB = colA + 32;
  f32x16 acc[2][2] = {};
  bf16x8 pb0 = ldfrag(&inwT[(size_t)colA * 384 + khalf]);
  bf16x8 pb1 = ldfrag(&inwT[(size_t)colB * 384 + khalf]);
  for (int ks = 0; ks < 24; ks++){
    int koff = ks * 16 + khalf;
    bf16x8 a0 = ldfrag(&A[lrow * 392 + koff]);
    bf16x8 a1 = ldfrag(&A[(32 + lrow) * 392 + koff]);
    bf16x8 b0 = pb0, b1 = pb1;
    if (ks < 23){
      pb0 = ldfrag(&inwT[(size_t)colA * 384 + koff + 16]);
      pb1 = ldfrag(&inwT[(size_t)colB * 384 + koff + 16]);
    }
    acc[0][0] = MFMA(a0, b0, acc[0][0]);
    acc[1][0] = MFMA(a1, b0, acc[1][0]);
    acc[0][1] = MFMA(a0, b1, acc[0][1]);
    acc[1][1] = MFMA(a1, b1, acc[1][1]);
  }
  float bs0 = in_b[colA], bs1 = in_b[colB];
  __syncthreads();            // A dead; reuse as SB[64][264]
#pragma unroll
  for (int rt = 0; rt < 2; rt++)
#pragma unroll
    for (int reg = 0; reg < 16; reg++){
      int row = rt * 32 + rowmap(reg, lane);
      A[row * 264 + colA] = f2bf(acc[rt][0][reg] + bs0);
      A[row * 264 + colB] = f2bf(acc[rt][1][reg] + bs1);
    }
  __syncthreads();
  {
    int r = t >> 2, s = t & 3;
    const uint4* src = (const uint4*)&A[r * 264 + s * 64];
    uint4* dst = (uint4*)(enc + ((size_t)m0 + r) * 256 + s * 64);
#pragma unroll
    for (int j = 0; j < 8; j++) dst[j] = src[j];
  }
}

// ------------------------------------------------ Q,K,V projections (MFMA)
// scalar 1-deep prefetch (round-3 proven). NOTE: never use register arrays
// with dynamic index in a rolled loop here (round-4: scratch demotion).
__global__ __launch_bounds__(256, 2) void k_qkv(const unsigned short* __restrict__ enc,
    const float* __restrict__ cur, const unsigned short* __restrict__ tem,
    const unsigned short* __restrict__ wq, const unsigned short* __restrict__ wk,
    const unsigned short* __restrict__ wv, const float* __restrict__ bq,
    const float* __restrict__ bk, const float* __restrict__ bv,
    int nbase, int lzero,
    unsigned short* __restrict__ qb, unsigned short* __restrict__ kb,
    unsigned short* __restrict__ vtb){
  __shared__ __align__(16) unsigned short A[64 * 296];   // 37,888 B
  __shared__ __align__(16) unsigned short SB[64 * 264];  // 33,792 B (=VT[256*66])
  int t = threadIdx.x;
  int nn = blockIdx.x >> 2;
  int n  = nbase + nn;
  int r0 = (blockIdx.x & 3) * 64;
  { // gather 64 ci rows -> bf16 LDS (stride 296)
    int r = t >> 2, c4 = t & 3;
    int grow = r0 + r;
    unsigned int* dst = (unsigned int*)&A[r * 296];
    if (grow < 128){
      const uint4* s4 = (const uint4*)(enc + ((size_t)n * 128 + grow) * 256 + c4 * 64);
      uint4* d4 = (uint4*)(dst + c4 * 32);
#pragma unroll
      for (int j = 0; j < 8; j++) d4[j] = s4[j];
    } else if (!lzero){
      const float4* s4 = (const float4*)(cur + ((size_t)n * 128 + grow - 128) * 256 + c4 * 64);
      unsigned int* d = dst + c4 * 32;
#pragma unroll
      for (int j = 0; j < 16; j++){
        float4 f = s4[j];
        d[2 * j]     = pack2(f.x, f.y);
        d[2 * j + 1] = pack2(f.z, f.w);
      }
    } else {
      uint4* d4 = (uint4*)(dst + c4 * 32);
      uint4 z = make_uint4(0, 0, 0, 0);
#pragma unroll
      for (int j = 0; j < 8; j++) d4[j] = z;
    }
    int jr = (grow < 128) ? grow : grow - 128;
    ((uint4*)(dst + 128))[c4] = ((const uint4*)(tem + ((size_t)n * 128 + jr) * 32))[c4];
  }
  __syncthreads();
  int w = t >> 6, lane = t & 63;
  int lrow = lane & 31, khalf = (lane >> 5) * 8;
  int colA = (w * 2) * 32 + lrow, colB = colA + 32;

  // write C-regs -> SB -> coalesced global
  auto store_rc = [&](f32x16 (*acc)[2], const float* bias, unsigned short* out){
    float bs0 = bias[colA], bs1 = bias[colB];
    __syncthreads();
#pragma unroll
    for (int rt = 0; rt < 2; rt++)
#pragma unroll
      for (int reg = 0; reg < 16; reg++){
        int row = rt * 32 + rowmap(reg, lane);
        SB[row * 264 + colA] = f2bf(acc[rt][0][reg] + bs0);
        SB[row * 264 + colB] = f2bf(acc[rt][1][reg] + bs1);
      }
    __syncthreads();
    int r = t >> 2, s = t & 3;
    const uint4* src = (const uint4*)&SB[r * 264 + s * 64];
    uint4* dst = (uint4*)(out + ((size_t)nn * 256 + r0 + r) * 256 + s * 64);
#pragma unroll
    for (int j = 0; j < 8; j++) dst[j] = src[j];
  };

  // ---- pass 1: Q and K share A fragments (scalar 1-deep B prefetch) ----
  {
    f32x16 aq[2][2] = {}, ak[2][2] = {};
    bf16x8 pq0 = ldfrag(&wq[(size_t)colA * 288 + khalf]);
    bf16x8 pq1 = ldfrag(&wq[(size_t)colB * 288 + khalf]);
    bf16x8 pk0 = ldfrag(&wk[(size_t)colA * 288 + khalf]);
    bf16x8 pk1 = ldfrag(&wk[(size_t)colB * 288 + khalf]);
    for (int ks = 0; ks < 18; ks++){
      int koff = ks * 16 + khalf;
      bf16x8 a0 = ldfrag(&A[lrow * 296 + koff]);
      bf16x8 a1 = ldfrag(&A[(32 + lrow) * 296 + koff]);
      bf16x8 q0 = pq0, q1 = pq1, k0 = pk0, k1 = pk1;
      if (ks < 17){
        pq0 = ldfrag(&wq[(size_t)colA * 288 + koff + 16]);
        pq1 = ldfrag(&wq[(size_t)colB * 288 + koff + 16]);
        pk0 = ldfrag(&wk[(size_t)colA * 288 + koff + 16]);
        pk1 = ldfrag(&wk[(size_t)colB * 288 + koff + 16]);
      }
      aq[0][0] = MFMA(a0, q0, aq[0][0]);
      aq[1][0] = MFMA(a1, q0, aq[1][0]);
      aq[0][1] = MFMA(a0, q1, aq[0][1]);
      aq[1][1] = MFMA(a1, q1, aq[1][1]);
      ak[0][0] = MFMA(a0, k0, ak[0][0]);
      ak[1][0] = MFMA(a1, k0, ak[1][0]);
      ak[0][1] = MFMA(a0, k1, ak[0][1]);
      ak[1][1] = MFMA(a1, k1, ak[1][1]);
    }
    store_rc(aq, bq, qb);
    store_rc(ak, bk, kb);
  }

  // ---- pass 2: V (transposed out, scalar 1-deep prefetch) ----
  {
    f32x16 av[2][2] = {};
    bf16x8 pv0 = ldfrag(&wv[(size_t)colA * 288 + khalf]);
    bf16x8 pv1 = ldfrag(&wv[(size_t)colB * 288 + khalf]);
    for (int ks = 0; ks < 18; ks++){
      int koff = ks * 16 + khalf;
      bf16x8 a0 = ldfrag(&A[lrow * 296 + koff]);
      bf16x8 a1 = ldfrag(&A[(32 + lrow) * 296 + koff]);
      bf16x8 v0 = pv0, v1 = pv1;
      if (ks < 17){
        pv0 = ldfrag(&wv[(size_t)colA * 288 + koff + 16]);
        pv1 = ldfrag(&wv[(size_t)colB * 288 + koff + 16]);
      }
      av[0][0] = MFMA(a0, v0, av[0][0]);
      av[1][0] = MFMA(a1, v0, av[1][0]);
      av[0][1] = MFMA(a0, v1, av[0][1]);
      av[1][1] = MFMA(a1, v1, av[1][1]);
    }
    float bs0 = bv[colA], bs1 = bv[colB];
    __syncthreads();
#pragma unroll
    for (int rt = 0; rt < 2; rt++)
#pragma unroll
      for (int reg = 0; reg < 16; reg++){
        int kl = rt * 32 + rowmap(reg, lane);
        SB[colA * 66 + kl] = f2bf(av[rt][0][reg] + bs0);
        SB[colB * 66 + kl] = f2bf(av[rt][1][reg] + bs1);
      }
    __syncthreads();
#pragma unroll
    for (int it = 0; it < 8; it++){
      int d = it * 32 + (t >> 3), j = t & 7;
      const unsigned int* vs = (const unsigned int*)&SB[d * 66];
      uint4 val = make_uint4(vs[j * 4], vs[j * 4 + 1], vs[j * 4 + 2], vs[j * 4 + 3]);
      *(uint4*)(vtb + ((size_t)nn * 256 + d) * 256 + r0 + j * 8) = val;
    }
  }
}

// ------------------------------------------------ attention v3
// Block = one nn x 64 q-rows, 4 waves. Wave (qt=w>>1, kh=w&1): scores for its
// 32q x 128-key-half (s[4], half the regs of v1) -> P-half into per-qtile LDS
// buffer; one barrier + LDS row-sum exchange; PV for its 128-d-half over all
// 256 keys (ov[4]). Peak ~110 VGPR -> 4 waves/SIMD; LDS ~35 KB -> 4 blocks/CU.
__global__ __launch_bounds__(256, 4) void k_attn(const unsigned short* __restrict__ qb,
    const unsigned short* __restrict__ kb, const unsigned short* __restrict__ vtb,
    unsigned short* __restrict__ enc, float* __restrict__ cur,
    const float* __restrict__ tim, int nbase, int lzero, int hsel,
    float* __restrict__ feat){
  __shared__ __align__(16) unsigned short P2[2][32 * 264];  // 33,792 B
  __shared__ float SM[2][2][32];
  __shared__ float TS[128];
  __shared__ unsigned long long MS[2];
  int t = threadIdx.x;
  int nn = blockIdx.x >> 2;
  int n  = nbase + nn;
  int qbase = (blockIdx.x & 3) * 64;
  int w = t >> 6, lane = t & 63;
  int lrow = lane & 31, kh8 = (lane >> 5) * 8;
  int qt = w >> 1, kh = w & 1;
  int qrow = qbase + qt * 32;
  if (t < 128) TS[t] = tim[(size_t)n * 128 + t];
  __syncthreads();
  if (w == 0){
    unsigned long long m0 = __ballot(TS[lane] > 0.0f);
    unsigned long long m1 = __ballot(TS[64 + lane] > 0.0f);
    if (lane == 0){ MS[0] = m0; MS[1] = m1; }
  }
  __syncthreads();
  bool xw = (qrow < 128);   // wave-uniform
  unsigned int fmbits = 0;  // fully-masked enc rows -> uniform softmax
  if (xw){
    unsigned long long km0 = MS[0], km1 = MS[1];
#pragma unroll
    for (int reg = 0; reg < 16; reg++){
      int Q = qrow + rowmap(reg, lane);      // < 128; keys [0,Q) relevant
      unsigned long long a = (Q >= 64) ? km0 : (km0 & ((1ull << Q) - 1ull));
      int c = __popcll(a);
      if (Q > 64) c += __popcll(km1 & ((1ull << (Q - 64)) - 1ull));
      if (c == 0) fmbits |= 1u << reg;
    }
  }
  const unsigned short* qn = qb  + (size_t)nn * 65536;
  const unsigned short* kn = kb  + (size_t)nn * 65536;
  const unsigned short* vn = vtb + (size_t)nn * 65536;
  unsigned short* myP = P2[qt];
  float sumacc[16];
#pragma unroll
  for (int i = 0; i < 16; i++) sumacc[i] = 0.0f;

  // ---- scores: 32q x 128 keys (this wave's key-half) ----
  f32x16 s[4] = {};
#pragma unroll
  for (int ks = 0; ks < 16; ks++){
    int koff = ks * 16 + kh8;
    bf16x8 a = ldfrag(&qn[(size_t)(qrow + lrow) * 256 + koff]);
#pragma unroll
    for (int ct = 0; ct < 4; ct++){
      bf16x8 b = ldfrag(&kn[(size_t)(kh * 128 + ct * 32 + lrow) * 256 + koff]);
      s[ct] = MFMA(a, b, s[ct]);
    }
  }
  // ---- mask + exp + P write + partial row sums ----
#pragma unroll
  for (int ct = 0; ct < 4; ct++){
    int key = kh * 128 + ct * 32 + lrow;
    bool keylo = (kh == 0);
    bool tzk = keylo ? (TS[key] == 0.0f) : false;
#pragma unroll
    for (int reg = 0; reg < 16; reg++){
      int rl = rowmap(reg, lane);
      int Q = qrow + rl;
      bool masked;
      if (xw)  masked = (key >= Q) || !keylo || tzk;
      else {
        int qq = Q - 128;
        masked = keylo ? ((key >= qq) || tzk) : ((key - 128) != qq);
      }
      float e = ((fmbits >> reg) & 1u) ? 0.00390625f
               : (masked ? 0.0f : __expf(s[ct][reg] * 0.0625f));
      sumacc[reg] += e;
      myP[rl * 264 + key] = f2bf(e);
    }
  }
  // reduce partial sums over the 32 key-lanes, publish per-row
#pragma unroll
  for (int reg = 0; reg < 16; reg++){
    float sv = sumacc[reg];
#pragma unroll
    for (int mk = 1; mk <= 16; mk <<= 1) sv += __shfl_xor(sv, mk, 64);
    if (lrow == 0) SM[qt][kh][rowmap(reg, lane)] = sv;   // lanes 0 & 32
  }
  __syncthreads();   // P complete (both key-halves) + sums published
#pragma unroll
  for (int reg = 0; reg < 16; reg++){
    int rl = rowmap(reg, lane);
    sumacc[reg] = 1.0f / (SM[qt][0][rl] + SM[qt][1][rl]);
  }
  // ---- PV: 32q x 128d (this wave's d-half) over all 256 keys ----
  f32x16 ov[4] = {};
#pragma unroll
  for (int ks = 0; ks < 16; ks++){
    int koff = ks * 16 + kh8;
    bf16x8 a = ldfrag(&myP[lrow * 264 + koff]);
#pragma unroll
    for (int dt = 0; dt < 4; dt++){
      bf16x8 b = ldfrag(&vn[(size_t)(kh * 128 + dt * 32 + lrow) * 256 + koff]);
      ov[dt] = MFMA(a, b, ov[dt]);
    }
  }
  // ---- epilogue ----
  int d0 = kh * 128;
#pragma unroll
  for (int reg = 0; reg < 16; reg++){
    int rl = rowmap(reg, lane);
    int Q = qrow + rl;
    float rs = sumacc[reg];
    if (xw){
      size_t base = ((size_t)n * 128 + Q) * 256 + d0;
#pragma unroll
      for (int dt = 0; dt < 4; dt++)
        enc[base + dt * 32 + lrow] = f2bf(ov[dt][reg] * rs);
    } else {
      int qq = Q - 128;
      float tq = TS[qq];
      size_t base = ((size_t)n * 128 + qq) * 256 + d0;
      bool wf = (hsel >= 0) && (qq == 127);
      if (lzero){
#pragma unroll
        for (int dt = 0; dt < 4; dt++){
          float x = ov[dt][reg] * rs;
          float ex = __expf(2.0f * x);
          float th = (tq > 0.0f) ? (1.0f - 2.0f / (ex + 1.0f)) : 0.0f;
          cur[base + dt * 32 + lrow] = th;
          if (wf) feat[(size_t)n * 512 + hsel * 256 + d0 + dt * 32 + lrow] = th;
        }
      } else {
#pragma unroll
        for (int dt = 0; dt < 4; dt++){
          float c = cur[base + dt * 32 + lrow];
          if (tq > 0.0f){
            float x = ov[dt][reg] * rs;
            float ex = __expf(2.0f * x);
            c += 1.0f - 2.0f / (ex + 1.0f);
            cur[base + dt * 32 + lrow] = c;
          }
          if (wf) feat[(size_t)n * 512 + hsel * 256 + d0 + dt * 32 + lrow] = c;
        }
      }
    }
  }
}

// ------------------------------------------------ output MLP head
__global__ __launch_bounds__(256) void k_mlp(const float* __restrict__ feat,
    const float* __restrict__ w1, const float* __restrict__ b1,
    const float* __restrict__ w2, const float* __restrict__ b2,
    float* __restrict__ out){
  __shared__ float F[512];
  __shared__ float red[4];
  int n = blockIdx.x, t = threadIdx.x;
  F[t]       = feat[(size_t)n * 512 + t];
  F[t + 256] = feat[(size_t)n * 512 + 256 + t];
  __syncthreads();
  float acc = 0.0f;
  for (int k4 = 0; k4 < 128; k4++){
    float b0v = w1[(k4 * 4 + 0) * 256 + t];
    float b1v = w1[(k4 * 4 + 1) * 256 + t];
    float b2v = w1[(k4 * 4 + 2) * 256 + t];
    float b3v = w1[(k4 * 4 + 3) * 256 + t];
    const float4 f = *(const float4*)&F[k4 * 4];
    acc = fmaf(f.x, b0v, fmaf(f.y, b1v, fmaf(f.z, b2v, fmaf(f.w, b3v, acc))));
  }
  acc += b1[t];
  float g = 0.5f * acc * (1.0f + erff(acc * 0.7071067811865475f));
  float part = g * w2[t];
#pragma unroll
  for (int mk = 1; mk < 64; mk <<= 1) part += __shfl_xor(part, mk, 64);
  if ((t & 63) == 0) red[t >> 6] = part;
  __syncthreads();
  if (t == 0) out[n] = red[0] + red[1] + red[2] + red[3] + b2[0];
}

// ------------------------------------------------ launch
extern "C" void kernel_launch(void* const* d_in, const int* in_sizes, int n_in,
                              void* d_out, int out_size, void* d_ws, size_t ws_size,
                              hipStream_t stream){
  const int*   subj = (const int*)  d_in[0];
  const int*   obj  = (const int*)  d_in[1];
  const int*   rel  = (const int*)  d_in[2];
  const float* tim  = (const float*)d_in[3];
  const float* ent  = (const float*)d_in[4];
  const float* rele = (const float*)d_in[5];
  const float* in_w = (const float*)d_in[6];
  const float* in_b = (const float*)d_in[7];
  const float* q_w  = (const float*)d_in[8];
  const float* q_b  = (const float*)d_in[9];
  const float* k_w  = (const float*)d_in[10];
  const float* k_b  = (const float*)d_in[11];
  const float* v_w  = (const float*)d_in[12];
  const float* v_b  = (const float*)d_in[13];
  const float* w1   = (const float*)d_in[14];
  const float* b1   = (const float*)d_in[15];
  const float* w2   = (const float*)d_in[16];
  const float* b2   = (const float*)d_in[17];

  // choose chunking from ws_size: full (1 chunk, ~295 MiB) if it fits,
  // else the proven 2-chunk layout (~199 MiB).
  const size_t FULL_BYTES = 309198848ull;
  int nchunks = (ws_size >= FULL_BYTES) ? 1 : 2;
  int nnz = 512 / nchunks;                 // sequences per chunk
  size_t qkvsz = (size_t)nnz * 65536 * 2;  // bytes per Q/K/V buffer

  char* ws = (char*)d_ws;
  size_t off = 0;
  unsigned short* tem  = (unsigned short*)(ws + off); off += 4194304;
  float*          cur  = (float*)(ws + off);          off += 67108864;
  unsigned short* enc  = (unsigned short*)(ws + off); off += 33554432;
  unsigned short* qb   = (unsigned short*)(ws + off); off += qkvsz;
  unsigned short* kb   = (unsigned short*)(ws + off); off += qkvsz;
  unsigned short* vtb  = (unsigned short*)(ws + off); off += qkvsz;
  float*          feat = (float*)(ws + off);          off += 1048576;
  unsigned short* wT   = (unsigned short*)(ws + off); off += 1966080;
  float* out = (float*)d_out;

  k_wprep<<<3840, 256, 0, stream>>>(in_w, q_w, k_w, v_w, wT);
  k_temporal<<<4096, 256, 0, stream>>>(tim, (unsigned int*)tem);
  k_inproj<<<1024, 256, 0, stream>>>(subj, obj, rel, ent, rele, wT, in_b, enc);

  for (int h = 0; h < 2; h++){
    for (int l = 0; l < 2; l++){
      int o = h * 2 + l;
      int lzero = (l == 0) ? 1 : 0;
      int hsel = (l == 1) ? h : -1;
      const unsigned short* wq = wT + 98304 + (size_t)(o * 3 + 0) * 73728;
      const unsigned short* wk = wT + 98304 + (size_t)(o * 3 + 1) * 73728;
      const unsigned short* wv = wT + 98304 + (size_t)(o * 3 + 2) * 73728;
      for (int c = 0; c < nchunks; c++){
        k_qkv<<<nnz * 4, 256, 0, stream>>>(enc, cur, tem, wq, wk, wv,
            q_b + o * 256, k_b + o * 256, v_b + o * 256, c * nnz, lzero,
            qb, kb, vtb);
        k_attn<<<nnz * 4, 256, 0, stream>>>(qb, kb, vtb, enc, cur, tim,
            c * nnz, lzero, hsel, feat);
      }
    }
  }
  k_mlp<<<512, 256, 0, stream>>>(feat, w1, b1, w2, b2, out);
}

// Round 7
// 1566.430 us; speedup vs baseline: 1.3356x; 1.3356x over previous
//
#include <hip/hip_runtime.h>
#include <math.h>

typedef __bf16 bf16x8 __attribute__((ext_vector_type(8)));
typedef float  f32x16 __attribute__((ext_vector_type(16)));

static __device__ __forceinline__ f32x16 MFMA(bf16x8 a, bf16x8 b, f32x16 c){
  return __builtin_amdgcn_mfma_f32_32x32x16_bf16(a, b, c, 0, 0, 0);
}
static __device__ __forceinline__ unsigned short f2bf(float x){
  unsigned int u = __builtin_bit_cast(unsigned int, x);
  u += 0x7fffu + ((u >> 16) & 1u);   // RNE
  return (unsigned short)(u >> 16);
}
static __device__ __forceinline__ unsigned int pack2(float a, float b){
  return ((unsigned int)f2bf(b) << 16) | (unsigned int)f2bf(a);
}
static __device__ __forceinline__ bf16x8 ldfrag(const unsigned short* p){
  return __builtin_bit_cast(bf16x8, *(const uint4*)p);
}
// C-layout row for 32x32x16: row = (reg&3) + 8*(reg>>2) + 4*(lane>>5)
static __device__ __forceinline__ int rowmap(int reg, int lane){
  return (reg & 3) + 8 * (reg >> 2) + 4 * (lane >> 5);
}

// ------------------------------------------------ weight transpose+cast (once)
__global__ __launch_bounds__(256) void k_wprep(const float* __restrict__ in_w,
    const float* __restrict__ q_w, const float* __restrict__ k_w,
    const float* __restrict__ v_w, unsigned short* __restrict__ wT){
  int idx = blockIdx.x * 256 + threadIdx.x;   // 983040 total
  float v;
  if (idx < 98304){
    int c = idx / 384, k = idx % 384;
    v = in_w[k * 256 + c];
  } else {
    int e = idx - 98304;
    int m = e / 73728, r = e % 73728;
    int c = r / 288, k = r % 288;
    int p = m % 3, layer = m / 3;
    const float* src = (p == 0) ? q_w : (p == 1) ? k_w : v_w;
    v = src[(size_t)layer * 73728 + k * 256 + c];
  }
  wT[idx] = f2bf(v);
}

// ------------------------------------------------ temporal emb (bf16, masked)
__global__ __launch_bounds__(256) void k_temporal(const float* __restrict__ tim,
                                                  unsigned int* __restrict__ tem){
  int idx = blockIdx.x * 256 + threadIdx.x;   // 65536*16
  int i = idx & 15, m = idx >> 4;
  float t = tim[m];
  float np = (t > 0.0f) ? 1.0f : 0.0f;
  float dv = expf((float)(2 * i) * (-0.28782313662425576f));
  float arg = t * dv;
  tem[m * 16 + i] = pack2(sinf(arg) * np, cosf(arg) * np);
}

// ------------------------------------------------ input projection (MFMA)
__global__ __launch_bounds__(256, 2) void k_inproj(const int* __restrict__ subj,
    const int* __restrict__ obj, const int* __restrict__ rel,
    const float* __restrict__ ent, const float* __restrict__ rele,
    const unsigned short* __restrict__ inwT, const float* __restrict__ in_b,
    unsigned short* __restrict__ enc){
  __shared__ __align__(16) unsigned short A[64 * 392];  // reused as SB[64*264] after
  int t = threadIdx.x;
  int m0 = blockIdx.x * 64;
  { // gather 64 rows of concat(ent[s],ent[o],rel[r]) as bf16
    int r = t >> 2, c = t & 3;
    int m = m0 + r;
    const float4* s0 = (const float4*)(ent  + (size_t)subj[m] * 128 + c * 32);
    const float4* s1 = (const float4*)(ent  + (size_t)obj[m]  * 128 + c * 32);
    const float4* s2 = (const float4*)(rele + (size_t)rel[m]  * 128 + c * 32);
    unsigned int* dst = (unsigned int*)&A[r * 392];
#pragma unroll
    for (int j = 0; j < 8; j++){
      float4 f0 = s0[j], f1 = s1[j], f2 = s2[j];
      dst[c * 16 + 2 * j]           = pack2(f0.x, f0.y);
      dst[c * 16 + 2 * j + 1]       = pack2(f0.z, f0.w);
      dst[64 + c * 16 + 2 * j]      = pack2(f1.x, f1.y);
      dst[64 + c * 16 + 2 * j + 1]  = pack2(f1.z, f1.w);
      dst[128 + c * 16 + 2 * j]     = pack2(f2.x, f2.y);
      dst[128 + c * 16 + 2 * j + 1] = pack2(f2.z, f2.w);
    }
  }
  __syncthreads();
  int w = t >> 6, lane = t & 63;
  int lrow = lane & 31, khalf = (lane >> 5) * 8;
  int colA = (w * 2) * 32 + lrow, colB = colA + 32;
  f32x16 acc[2][2] = {};
  bf16x8 pb0 = ldfrag(&inwT[(size_t)colA * 384 + khalf]);
  bf16x8 pb1 = ldfrag(&inwT[(size_t)colB * 384 + khalf]);
  for (int ks = 0; ks < 24; ks++){
    int koff = ks * 16 + khalf;
    bf16x8 a0 = ldfrag(&A[lrow * 392 + koff]);
    bf16x8 a1 = ldfrag(&A[(32 + lrow) * 392 + koff]);
    bf16x8 b0 = pb0, b1 = pb1;
    if (ks < 23){
      pb0 = ldfrag(&inwT[(size_t)colA * 384 + koff + 16]);
      pb1 = ldfrag(&inwT[(size_t)colB * 384 + koff + 16]);
    }
    acc[0][0] = MFMA(a0, b0, acc[0][0]);
    acc[1][0] = MFMA(a1, b0, acc[1][0]);
    acc[0][1] = MFMA(a0, b1, acc[0][1]);
    acc[1][1] = MFMA(a1, b1, acc[1][1]);
  }
  float bs0 = in_b[colA], bs1 = in_b[colB];
  __syncthreads();            // A dead; reuse as SB[64][264]
#pragma unroll
  for (int rt = 0; rt < 2; rt++)
#pragma unroll
    for (int reg = 0; reg < 16; reg++){
      int row = rt * 32 + rowmap(reg, lane);
      A[row * 264 + colA] = f2bf(acc[rt][0][reg] + bs0);
      A[row * 264 + colB] = f2bf(acc[rt][1][reg] + bs1);
    }
  __syncthreads();
  {
    int r = t >> 2, s = t & 3;
    const uint4* src = (const uint4*)&A[r * 264 + s * 64];
    uint4* dst = (uint4*)(enc + ((size_t)m0 + r) * 256 + s * 64);
#pragma unroll
    for (int j = 0; j < 8; j++) dst[j] = src[j];
  }
}

// ------------------------------------------------ Q,K,V projections (MFMA)
// scalar 1-deep prefetch (round-3 proven). NOTE: never use register arrays
// with dynamic index in a rolled loop here (round-4: scratch demotion).
__global__ __launch_bounds__(256, 2) void k_qkv(const unsigned short* __restrict__ enc,
    const float* __restrict__ cur, const unsigned short* __restrict__ tem,
    const unsigned short* __restrict__ wq, const unsigned short* __restrict__ wk,
    const unsigned short* __restrict__ wv, const float* __restrict__ bq,
    const float* __restrict__ bk, const float* __restrict__ bv,
    int nbase, int lzero,
    unsigned short* __restrict__ qb, unsigned short* __restrict__ kb,
    unsigned short* __restrict__ vtb){
  __shared__ __align__(16) unsigned short A[64 * 296];   // 37,888 B
  __shared__ __align__(16) unsigned short SB[64 * 264];  // 33,792 B (=VT[256*66])
  int t = threadIdx.x;
  int nn = blockIdx.x >> 2;
  int n  = nbase + nn;
  int r0 = (blockIdx.x & 3) * 64;
  { // gather 64 ci rows -> bf16 LDS (stride 296)
    int r = t >> 2, c4 = t & 3;
    int grow = r0 + r;
    unsigned int* dst = (unsigned int*)&A[r * 296];
    if (grow < 128){
      const uint4* s4 = (const uint4*)(enc + ((size_t)n * 128 + grow) * 256 + c4 * 64);
      uint4* d4 = (uint4*)(dst + c4 * 32);
#pragma unroll
      for (int j = 0; j < 8; j++) d4[j] = s4[j];
    } else if (!lzero){
      const float4* s4 = (const float4*)(cur + ((size_t)n * 128 + grow - 128) * 256 + c4 * 64);
      unsigned int* d = dst + c4 * 32;
#pragma unroll
      for (int j = 0; j < 16; j++){
        float4 f = s4[j];
        d[2 * j]     = pack2(f.x, f.y);
        d[2 * j + 1] = pack2(f.z, f.w);
      }
    } else {
      uint4* d4 = (uint4*)(dst + c4 * 32);
      uint4 z = make_uint4(0, 0, 0, 0);
#pragma unroll
      for (int j = 0; j < 8; j++) d4[j] = z;
    }
    int jr = (grow < 128) ? grow : grow - 128;
    ((uint4*)(dst + 128))[c4] = ((const uint4*)(tem + ((size_t)n * 128 + jr) * 32))[c4];
  }
  __syncthreads();
  int w = t >> 6, lane = t & 63;
  int lrow = lane & 31, khalf = (lane >> 5) * 8;
  int colA = (w * 2) * 32 + lrow, colB = colA + 32;

  // write C-regs -> SB -> coalesced global
  auto store_rc = [&](f32x16 (*acc)[2], const float* bias, unsigned short* out){
    float bs0 = bias[colA], bs1 = bias[colB];
    __syncthreads();
#pragma unroll
    for (int rt = 0; rt < 2; rt++)
#pragma unroll
      for (int reg = 0; reg < 16; reg++){
        int row = rt * 32 + rowmap(reg, lane);
        SB[row * 264 + colA] = f2bf(acc[rt][0][reg] + bs0);
        SB[row * 264 + colB] = f2bf(acc[rt][1][reg] + bs1);
      }
    __syncthreads();
    int r = t >> 2, s = t & 3;
    const uint4* src = (const uint4*)&SB[r * 264 + s * 64];
    uint4* dst = (uint4*)(out + ((size_t)nn * 256 + r0 + r) * 256 + s * 64);
#pragma unroll
    for (int j = 0; j < 8; j++) dst[j] = src[j];
  };

  // ---- pass 1: Q and K share A fragments (scalar 1-deep B prefetch) ----
  {
    f32x16 aq[2][2] = {}, ak[2][2] = {};
    bf16x8 pq0 = ldfrag(&wq[(size_t)colA * 288 + khalf]);
    bf16x8 pq1 = ldfrag(&wq[(size_t)colB * 288 + khalf]);
    bf16x8 pk0 = ldfrag(&wk[(size_t)colA * 288 + khalf]);
    bf16x8 pk1 = ldfrag(&wk[(size_t)colB * 288 + khalf]);
    for (int ks = 0; ks < 18; ks++){
      int koff = ks * 16 + khalf;
      bf16x8 a0 = ldfrag(&A[lrow * 296 + koff]);
      bf16x8 a1 = ldfrag(&A[(32 + lrow) * 296 + koff]);
      bf16x8 q0 = pq0, q1 = pq1, k0 = pk0, k1 = pk1;
      if (ks < 17){
        pq0 = ldfrag(&wq[(size_t)colA * 288 + koff + 16]);
        pq1 = ldfrag(&wq[(size_t)colB * 288 + koff + 16]);
        pk0 = ldfrag(&wk[(size_t)colA * 288 + koff + 16]);
        pk1 = ldfrag(&wk[(size_t)colB * 288 + koff + 16]);
      }
      aq[0][0] = MFMA(a0, q0, aq[0][0]);
      aq[1][0] = MFMA(a1, q0, aq[1][0]);
      aq[0][1] = MFMA(a0, q1, aq[0][1]);
      aq[1][1] = MFMA(a1, q1, aq[1][1]);
      ak[0][0] = MFMA(a0, k0, ak[0][0]);
      ak[1][0] = MFMA(a1, k0, ak[1][0]);
      ak[0][1] = MFMA(a0, k1, ak[0][1]);
      ak[1][1] = MFMA(a1, k1, ak[1][1]);
    }
    store_rc(aq, bq, qb);
    store_rc(ak, bk, kb);
  }

  // ---- pass 2: V (transposed out, scalar 1-deep prefetch) ----
  {
    f32x16 av[2][2] = {};
    bf16x8 pv0 = ldfrag(&wv[(size_t)colA * 288 + khalf]);
    bf16x8 pv1 = ldfrag(&wv[(size_t)colB * 288 + khalf]);
    for (int ks = 0; ks < 18; ks++){
      int koff = ks * 16 + khalf;
      bf16x8 a0 = ldfrag(&A[lrow * 296 + koff]);
      bf16x8 a1 = ldfrag(&A[(32 + lrow) * 296 + koff]);
      bf16x8 v0 = pv0, v1 = pv1;
      if (ks < 17){
        pv0 = ldfrag(&wv[(size_t)colA * 288 + koff + 16]);
        pv1 = ldfrag(&wv[(size_t)colB * 288 + koff + 16]);
      }
      av[0][0] = MFMA(a0, v0, av[0][0]);
      av[1][0] = MFMA(a1, v0, av[1][0]);
      av[0][1] = MFMA(a0, v1, av[0][1]);
      av[1][1] = MFMA(a1, v1, av[1][1]);
    }
    float bs0 = bv[colA], bs1 = bv[colB];
    __syncthreads();
#pragma unroll
    for (int rt = 0; rt < 2; rt++)
#pragma unroll
      for (int reg = 0; reg < 16; reg++){
        int kl = rt * 32 + rowmap(reg, lane);
        SB[colA * 66 + kl] = f2bf(av[rt][0][reg] + bs0);
        SB[colB * 66 + kl] = f2bf(av[rt][1][reg] + bs1);
      }
    __syncthreads();
#pragma unroll
    for (int it = 0; it < 8; it++){
      int d = it * 32 + (t >> 3), j = t & 7;
      const unsigned int* vs = (const unsigned int*)&SB[d * 66];
      uint4 val = make_uint4(vs[j * 4], vs[j * 4 + 1], vs[j * 4 + 2], vs[j * 4 + 3]);
      *(uint4*)(vtb + ((size_t)nn * 256 + d) * 256 + r0 + j * 8) = val;
    }
  }
}

// ------------------------------------------------ attention v4
// v1 topology (2 blocks/nn, 4 waves of 32q x 256keys — best measured, FETCH
// 1.24x ideal) + STRUCTURAL TILE SKIPPING: wave w computes only key-tiles
// ct<=w (+ diag tile 4+w for cur waves) — 24/64 tiles per nn. Rows with no
// unmasked key (fmbits, typically q=0 only) force their wave to all 8 tiles,
// reproducing the uniform-1/256 softmax. PV fused per-tile through a tiny
// per-wave 32x40 LDS buffer (C->A transform); no barriers after startup.
__global__ __launch_bounds__(256, 2) void k_attn(const unsigned short* __restrict__ qb,
    const unsigned short* __restrict__ kb, const unsigned short* __restrict__ vtb,
    unsigned short* __restrict__ enc, float* __restrict__ cur,
    const float* __restrict__ tim, int nbase, int lzero, int hsel,
    float* __restrict__ feat){
  __shared__ __align__(16) unsigned short PB[4][32 * 40];  // 10,240 B
  __shared__ float TS[128];
  __shared__ unsigned long long MS[2];
  int t = threadIdx.x;
  int nn = blockIdx.x >> 1;
  int n  = nbase + nn;
  int q0 = (blockIdx.x & 1) * 128;
  int w = t >> 6, lane = t & 63;
  int lrow = lane & 31, kh8 = (lane >> 5) * 8;
  int qrow = q0 + w * 32;
  if (t < 128) TS[t] = tim[(size_t)n * 128 + t];
  __syncthreads();
  if (w == 0){
    unsigned long long m0 = __ballot(TS[lane] > 0.0f);
    unsigned long long m1 = __ballot(TS[64 + lane] > 0.0f);
    if (lane == 0){ MS[0] = m0; MS[1] = m1; }
  }
  __syncthreads();
  bool xw = (qrow < 128);   // wave-uniform
  unsigned int fmbits = 0;  // fully-masked enc rows -> uniform softmax
  if (xw){
    unsigned long long km0 = MS[0], km1 = MS[1];
#pragma unroll
    for (int reg = 0; reg < 16; reg++){
      int Q = qrow + rowmap(reg, lane);      // < 128; keys [0,Q) relevant
      unsigned long long a = (Q >= 64) ? km0 : (km0 & ((1ull << Q) - 1ull));
      int c = __popcll(a);
      if (Q > 64) c += __popcll(km1 & ((1ull << (Q - 64)) - 1ull));
      if (c == 0) fmbits |= 1u << reg;
    }
  }
  bool fmany = (__ballot(fmbits != 0) != 0ull);   // wave-uniform
  int diagct = xw ? -1 : 4 + w;
  const unsigned short* qn = qb  + (size_t)nn * 65536;
  const unsigned short* kn = kb  + (size_t)nn * 65536;
  const unsigned short* vn = vtb + (size_t)nn * 65536;
  unsigned short* myP = PB[w];
  // preload Q fragments (reused across all active tiles)
  bf16x8 qf[16];
#pragma unroll
  for (int ks = 0; ks < 16; ks++)
    qf[ks] = ldfrag(&qn[(size_t)(qrow + lrow) * 256 + ks * 16 + kh8]);

  float sumacc[16];
#pragma unroll
  for (int i = 0; i < 16; i++) sumacc[i] = 0.0f;
  f32x16 ov[8] = {};

#pragma unroll
  for (int ct = 0; ct < 8; ct++){
    bool active = fmany || (ct <= w) || (ct == diagct);  // wave-uniform
    if (!active) continue;
    // ---- scores for this 32-key tile ----
    f32x16 s = {};
#pragma unroll
    for (int ks = 0; ks < 16; ks++){
      bf16x8 b = ldfrag(&kn[(size_t)(ct * 32 + lrow) * 256 + ks * 16 + kh8]);
      s = MFMA(qf[ks], b, s);
    }
    int key = ct * 32 + lrow;
    bool keylo = (ct < 4);
    bool tzk = keylo ? (TS[key] == 0.0f) : false;
    // ---- mask + exp + P tile (per-wave LDS, stride 40) ----
#pragma unroll
    for (int reg = 0; reg < 16; reg++){
      int rl = rowmap(reg, lane);
      int Q = qrow + rl;
      bool masked;
      if (xw)  masked = (key >= Q) || !keylo || tzk;
      else {
        int qq = Q - 128;
        masked = keylo ? ((key >= qq) || tzk) : ((key - 128) != qq);
      }
      float e = ((fmbits >> reg) & 1u) ? 0.00390625f
               : (masked ? 0.0f : __expf(s[reg] * 0.0625f));
      sumacc[reg] += e;
      myP[rl * 40 + (key & 31)] = f2bf(e);
    }
    // ---- PV accumulate for this tile (C->A via per-wave LDS) ----
#pragma unroll
    for (int hs = 0; hs < 2; hs++){
      bf16x8 a = ldfrag(&myP[lrow * 40 + hs * 16 + kh8]);
#pragma unroll
      for (int dt = 0; dt < 8; dt++){
        bf16x8 b = ldfrag(&vn[(size_t)(dt * 32 + lrow) * 256 + ct * 32 + hs * 16 + kh8]);
        ov[dt] = MFMA(a, b, ov[dt]);
      }
    }
  }
  // row-sum reduce across the 32 key-lanes of each row
#pragma unroll
  for (int reg = 0; reg < 16; reg++){
    float sv = sumacc[reg];
#pragma unroll
    for (int mk = 1; mk <= 16; mk <<= 1) sv += __shfl_xor(sv, mk, 64);
    sumacc[reg] = 1.0f / sv;   // never 0: fm rows sum to 1; cur rows >=1 key
  }
  // ---- epilogue ----
#pragma unroll
  for (int reg = 0; reg < 16; reg++){
    int rl = rowmap(reg, lane);
    int Q = qrow + rl;
    float rs = sumacc[reg];
    if (xw){
      size_t base = ((size_t)n * 128 + Q) * 256;
#pragma unroll
      for (int dt = 0; dt < 8; dt++)
        enc[base + dt * 32 + lrow] = f2bf(ov[dt][reg] * rs);
    } else {
      int qq = Q - 128;
      float tq = TS[qq];
      size_t base = ((size_t)n * 128 + qq) * 256;
      bool wf = (hsel >= 0) && (qq == 127);
      if (lzero){
#pragma unroll
        for (int dt = 0; dt < 8; dt++){
          float x = ov[dt][reg] * rs;
          float ex = __expf(2.0f * x);
          float th = (tq > 0.0f) ? (1.0f - 2.0f / (ex + 1.0f)) : 0.0f;
          cur[base + dt * 32 + lrow] = th;
          if (wf) feat[(size_t)n * 512 + hsel * 256 + dt * 32 + lrow] = th;
        }
      } else {
#pragma unroll
        for (int dt = 0; dt < 8; dt++){
          float c = cur[base + dt * 32 + lrow];
          if (tq > 0.0f){
            float x = ov[dt][reg] * rs;
            float ex = __expf(2.0f * x);
            c += 1.0f - 2.0f / (ex + 1.0f);
            cur[base + dt * 32 + lrow] = c;
          }
          if (wf) feat[(size_t)n * 512 + hsel * 256 + dt * 32 + lrow] = c;
        }
      }
    }
  }
}

// ------------------------------------------------ output MLP head
__global__ __launch_bounds__(256) void k_mlp(const float* __restrict__ feat,
    const float* __restrict__ w1, const float* __restrict__ b1,
    const float* __restrict__ w2, const float* __restrict__ b2,
    float* __restrict__ out){
  __shared__ float F[512];
  __shared__ float red[4];
  int n = blockIdx.x, t = threadIdx.x;
  F[t]       = feat[(size_t)n * 512 + t];
  F[t + 256] = feat[(size_t)n * 512 + 256 + t];
  __syncthreads();
  float acc = 0.0f;
  for (int k4 = 0; k4 < 128; k4++){
    float b0v = w1[(k4 * 4 + 0) * 256 + t];
    float b1v = w1[(k4 * 4 + 1) * 256 + t];
    float b2v = w1[(k4 * 4 + 2) * 256 + t];
    float b3v = w1[(k4 * 4 + 3) * 256 + t];
    const float4 f = *(const float4*)&F[k4 * 4];
    acc = fmaf(f.x, b0v, fmaf(f.y, b1v, fmaf(f.z, b2v, fmaf(f.w, b3v, acc))));
  }
  acc += b1[t];
  float g = 0.5f * acc * (1.0f + erff(acc * 0.7071067811865475f));
  float part = g * w2[t];
#pragma unroll
  for (int mk = 1; mk < 64; mk <<= 1) part += __shfl_xor(part, mk, 64);
  if ((t & 63) == 0) red[t >> 6] = part;
  __syncthreads();
  if (t == 0) out[n] = red[0] + red[1] + red[2] + red[3] + b2[0];
}

// ------------------------------------------------ launch
extern "C" void kernel_launch(void* const* d_in, const int* in_sizes, int n_in,
                              void* d_out, int out_size, void* d_ws, size_t ws_size,
                              hipStream_t stream){
  const int*   subj = (const int*)  d_in[0];
  const int*   obj  = (const int*)  d_in[1];
  const int*   rel  = (const int*)  d_in[2];
  const float* tim  = (const float*)d_in[3];
  const float* ent  = (const float*)d_in[4];
  const float* rele = (const float*)d_in[5];
  const float* in_w = (const float*)d_in[6];
  const float* in_b = (const float*)d_in[7];
  const float* q_w  = (const float*)d_in[8];
  const float* q_b  = (const float*)d_in[9];
  const float* k_w  = (const float*)d_in[10];
  const float* k_b  = (const float*)d_in[11];
  const float* v_w  = (const float*)d_in[12];
  const float* v_b  = (const float*)d_in[13];
  const float* w1   = (const float*)d_in[14];
  const float* b1   = (const float*)d_in[15];
  const float* w2   = (const float*)d_in[16];
  const float* b2   = (const float*)d_in[17];

  // full (1 chunk, ~295 MiB) if it fits, else 2-chunk (~199 MiB).
  const size_t FULL_BYTES = 309198848ull;
  int nchunks = (ws_size >= FULL_BYTES) ? 1 : 2;
  int nnz = 512 / nchunks;                 // sequences per chunk
  size_t qkvsz = (size_t)nnz * 65536 * 2;  // bytes per Q/K/V buffer

  char* ws = (char*)d_ws;
  size_t off = 0;
  unsigned short* tem  = (unsigned short*)(ws + off); off += 4194304;
  float*          cur  = (float*)(ws + off);          off += 67108864;
  unsigned short* enc  = (unsigned short*)(ws + off); off += 33554432;
  unsigned short* qb   = (unsigned short*)(ws + off); off += qkvsz;
  unsigned short* kb   = (unsigned short*)(ws + off); off += qkvsz;
  unsigned short* vtb  = (unsigned short*)(ws + off); off += qkvsz;
  float*          feat = (float*)(ws + off);          off += 1048576;
  unsigned short* wT   = (unsigned short*)(ws + off); off += 1966080;
  float* out = (float*)d_out;

  k_wprep<<<3840, 256, 0, stream>>>(in_w, q_w, k_w, v_w, wT);
  k_temporal<<<4096, 256, 0, stream>>>(tim, (unsigned int*)tem);
  k_inproj<<<1024, 256, 0, stream>>>(subj, obj, rel, ent, rele, wT, in_b, enc);

  for (int h = 0; h < 2; h++){
    for (int l = 0; l < 2; l++){
      int o = h * 2 + l;
      int lzero = (l == 0) ? 1 : 0;
      int hsel = (l == 1) ? h : -1;
      const unsigned short* wq = wT + 98304 + (size_t)(o * 3 + 0) * 73728;
      const unsigned short* wk = wT + 98304 + (size_t)(o * 3 + 1) * 73728;
      const unsigned short* wv = wT + 98304 + (size_t)(o * 3 + 2) * 73728;
      for (int c = 0; c < nchunks; c++){
        k_qkv<<<nnz * 4, 256, 0, stream>>>(enc, cur, tem, wq, wk, wv,
            q_b + o * 256, k_b + o * 256, v_b + o * 256, c * nnz, lzero,
            qb, kb, vtb);
        k_attn<<<nnz * 2, 256, 0, stream>>>(qb, kb, vtb, enc, cur, tim,
            c * nnz, lzero, hsel, feat);
      }
    }
  }
  k_mlp<<<512, 256, 0, stream>>>(feat, w1, b1, w2, b2, out);
}